// Round 15
// baseline (5578.055 us; speedup 1.0000x reference)
//
#include <hip/hip_runtime.h>
#include <math.h>

#define B_   64
#define S_   3072
#define DIN  128
#define E_   64
#define H_   256
#define OUT_ 10
#define T_   1024

// workspace layout (bytes)
#define ACT_BYTES   (B_*E_*T_*4)              // actT[b][e][t] fp32 = 16 MB
#define HFINAL_OFF  ACT_BYTES
#define HFINAL_BYTES (B_*H_*4)                // 64 KB

typedef float f32x4 __attribute__((ext_vector_type(4)));
typedef _Float16 h16x2 __attribute__((ext_vector_type(2)));

#if defined(__has_builtin)
#  if __has_builtin(__builtin_amdgcn_fdot2)
#    define HAVE_FDOT2 1
#  endif
#endif

// f16x2 dot-accumulate: one v_dot2_f32_f16 if available, else fma_mix pattern
__device__ __forceinline__ float dot2acc(unsigned int w, unsigned int h, float acc) {
#ifdef HAVE_FDOT2
  union { unsigned int u; h16x2 v; } uw, uh;
  uw.u = w; uh.u = h;
  return __builtin_amdgcn_fdot2(uw.v, uh.v, acc, false);
#else
  union { unsigned int u; _Float16 f[2]; } uw, uh;
  uw.u = w; uh.u = h;
  acc = fmaf((float)uw.f[0], (float)uh.f[0], acc);  // fpext f16 -> v_fma_mix
  acc = fmaf((float)uw.f[1], (float)uh.f[1], acc);
  return acc;
#endif
}

__device__ __forceinline__ unsigned int pack2(float a, float b) {
  union { _Float16 f[2]; unsigned int u; } r;
  r.f[0] = (_Float16)a; r.f[1] = (_Float16)b;   // RNE converts
  return r.u;
}

__device__ __forceinline__ float fast_sigmoid(float x) {
  return __builtin_amdgcn_rcpf(1.0f + __expf(-x));
}
__device__ __forceinline__ float fast_tanh(float x) {
  return 2.0f * __builtin_amdgcn_rcpf(1.0f + __expf(-2.0f * x)) - 1.0f;
}

// ---------------------------------------------------------------------------
// Conv: normalize rows (L2 over D=128), conv1d k=3 stride=3, +bias, relu.
// (unchanged — validated in rounds 1-14)
// ---------------------------------------------------------------------------
__global__ __launch_bounds__(512, 1) void conv_kernel(
    const float* __restrict__ in,     // [B][S][DIN]
    const float* __restrict__ cw,     // [E][DIN][3]
    const float* __restrict__ cb,     // [E]
    float* __restrict__ actT)         // [B][E][T]
{
  extern __shared__ float xs[];                 // 192 rows x 128 f, swizzled
  float4* xs4 = (float4*)xs;
  const int bid = blockIdx.x;
  const int b  = bid >> 4;
  const int tb = bid & 15;
  const int tid = threadIdx.x;

  const float4* gin = (const float4*)(in + (size_t)b*S_*DIN + (size_t)tb*192*DIN);
  #pragma unroll
  for (int i = 0; i < 12; ++i) {
    int f4 = tid + i*512;
    int r = f4 >> 5, dq = f4 & 31;
    xs4[r*32 + (dq ^ (r & 7))] = gin[f4];
  }
  __syncthreads();

  const int wv = tid >> 6, ln = tid & 63;
  for (int rr = 0; rr < 24; ++rr) {
    int r = wv*24 + rr;
    int u = r*32 + ((ln >> 1) ^ (r & 7));
    float2* p = (float2*)((char*)xs + (size_t)u*16 + (size_t)(ln & 1)*8);
    float2 v = *p;
    float s = v.x*v.x + v.y*v.y;
    #pragma unroll
    for (int off = 32; off >= 1; off >>= 1) s += __shfl_xor(s, off);
    float inv = 1.0f / fmaxf(sqrtf(s), 1e-12f);
    v.x *= inv; v.y *= inv;
    *p = v;
  }
  __syncthreads();

  const int eo = __builtin_amdgcn_readfirstlane(wv);
  float acc[8];
  #pragma unroll
  for (int j = 0; j < 8; ++j) acc[j] = cb[eo*8 + j];

  const int r0 = 3*ln, r1 = 3*ln + 1, r2 = 3*ln + 2;
  #pragma unroll 4
  for (int dq = 0; dq < 32; ++dq) {
    float4 x0 = xs4[r0*32 + (dq ^ (r0 & 7))];
    float4 x1 = xs4[r1*32 + (dq ^ (r1 & 7))];
    float4 x2 = xs4[r2*32 + (dq ^ (r2 & 7))];
    #pragma unroll
    for (int j = 0; j < 8; ++j) {
      const float* wp = cw + (size_t)(eo*8 + j)*(DIN*3) + dq*12;  // uniform
      acc[j] += x0.x*wp[0] + x1.x*wp[1] + x2.x*wp[2]
              + x0.y*wp[3] + x1.y*wp[4] + x2.y*wp[5]
              + x0.z*wp[6] + x1.z*wp[7] + x2.z*wp[8]
              + x0.w*wp[9] + x1.w*wp[10] + x2.w*wp[11];
    }
  }

  const int tg = tb*64 + ln;
  #pragma unroll
  for (int j = 0; j < 8; ++j) {
    int e = eo*8 + j;
    actT[(size_t)b*E_*T_ + (size_t)e*T_ + tg] = fmaxf(acc[j], 0.0f);
  }
}

// ---------------------------------------------------------------------------
// LSTM — single-WG-per-batch, ZERO cross-WG exchange.
// 64 WGs x 1024 threads (16 waves). Thread (w,l): m=l&3 (gate),
// cell = w*16 + (l>>2) (0..255); row = m*256+cell. Each thread holds its
// FULL gate row as f16x2 in VGPRs (128+32 regs) — the whole 1024x320
// weight matrix is CU-resident in fp16 (0.65 MB; fp32's 1.31 MB did not fit,
// which forced rounds 2-14's cross-WG exchange at an invariant ~1.6us/step
// coherence RT). h,x live in 1.25 KB LDS (f16 pairs, double-buffered);
// GEMV = 160 v_dot2_f32_f16 broadcast-LDS reads; gates butterfly within
// each quad (shfl_xor 1,2 — r6-verified table); ONE __syncthreads per step.
// All state math (bias, gates sum, c, h) is fp32; only W and the dot
// operands are fp16 -> output error ~1e-4 vs 1.4e-3 threshold.
// ---------------------------------------------------------------------------
__global__ __launch_bounds__(1024, 1) void lstm_kernel(
    const float* __restrict__ actT,   // [B][E][T]
    const float* __restrict__ w_ih,   // [1024][64]
    const float* __restrict__ w_hh,   // [1024][256]
    const float* __restrict__ b_ih,
    const float* __restrict__ b_hh,
    float* __restrict__ hfinal)       // [B][H]
{
  __shared__ __align__(16) unsigned int h2[2][128];  // f16x2 pairs of h
  __shared__ __align__(16) unsigned int x2[2][32];   // f16x2 pairs of x

  const int g   = blockIdx.x;          // batch
  const int tid = threadIdx.x;
  const int w   = tid >> 6;
  const int l   = tid & 63;
  const int m   = l & 3;               // gate (i,f,g,o)
  const int cell = w*16 + (l >> 2);    // 0..255
  const int row  = m*256 + cell;       // gate row in [0,1024)

  // weights -> f16x2 VGPRs (static-indexed, fully unrolled)
  unsigned int wh[128], wx[32];
  {
    const float4* ph = (const float4*)(w_hh + (size_t)row*H_);
    #pragma unroll
    for (int i = 0; i < 64; ++i) {
      float4 v = ph[i];
      wh[2*i]   = pack2(v.x, v.y);
      wh[2*i+1] = pack2(v.z, v.w);
    }
    const float4* px = (const float4*)(w_ih + (size_t)row*E_);
    #pragma unroll
    for (int i = 0; i < 16; ++i) {
      float4 v = px[i];
      wx[2*i]   = pack2(v.x, v.y);
      wx[2*i+1] = pack2(v.z, v.w);
    }
  }
  const float bias = b_ih[row] + b_hh[row];

  // x loader role: threads 0..63, one e-row each
  const float* actp = actT + ((size_t)g*E_ + l)*T_;

  // prologue: h(0) = 0, stage x(0)
  if (tid < 128) h2[0][tid] = 0u;
  if (tid < 64) ((_Float16*)&x2[0][0])[tid] = (_Float16)actp[0];
  __syncthreads();

  float c = 0.0f;
  for (int t = 0; t < T_; ++t) {
    const int p = t & 1;

    // prefetch x(t+1) (global load in flight through the GEMV)
    float xval = 0.0f;
    if (tid < 64) xval = actp[(t + 1 < T_) ? (t + 1) : t];

    // full-row GEMV: 128 h-pairs + 32 x-pairs, broadcast LDS reads
    float a0 = bias, a1 = 0.0f, a2 = 0.0f, a3 = 0.0f;
    {
      const unsigned int* hp = &h2[p][0];
      #pragma unroll
      for (int i = 0; i < 128; i += 4) {
        uint4 hv = *(const uint4*)(hp + i);
        a0 = dot2acc(wh[i+0], hv.x, a0);
        a1 = dot2acc(wh[i+1], hv.y, a1);
        a2 = dot2acc(wh[i+2], hv.z, a2);
        a3 = dot2acc(wh[i+3], hv.w, a3);
      }
      const unsigned int* xp = &x2[p][0];
      #pragma unroll
      for (int i = 0; i < 32; i += 4) {
        uint4 xv = *(const uint4*)(xp + i);
        a0 = dot2acc(wx[i+0], xv.x, a0);
        a1 = dot2acc(wx[i+1], xv.y, a1);
        a2 = dot2acc(wx[i+2], xv.z, a2);
        a3 = dot2acc(wx[i+3], xv.w, a3);
      }
    }
    float acc = (a0 + a1) + (a2 + a3);

    // quad butterfly: all 4 gates of this cell into every quad lane
    float q1 = __shfl_xor(acc, 1);   // gate m^1
    float q2 = __shfl_xor(acc, 2);   // gate m^2
    float q3 = __shfl_xor(q1, 2);    // gate m^3
    float gi = (m==0)?acc:(m==1)?q1 :(m==2)?q2 :q3;
    float gf = (m==0)?q1 :(m==1)?acc:(m==2)?q3 :q2;
    float gg = (m==0)?q2 :(m==1)?q3 :(m==2)?acc:q1;
    float go = (m==0)?q3 :(m==1)?q2 :(m==2)?q1 :acc;

    float si = fast_sigmoid(gi);
    float sf = fast_sigmoid(gf);
    float so = fast_sigmoid(go);
    c = sf*c + si*fast_tanh(gg);
    float h = so*fast_tanh(c);

    // publish h(t+1), x(t+1) into the next-parity LDS buffers
    if (m == 0) ((_Float16*)&h2[p ^ 1][0])[cell] = (_Float16)h;
    if (tid < 64) ((_Float16*)&x2[p ^ 1][0])[tid] = (_Float16)xval;
    if (m == 0 && t == T_ - 1) hfinal[(size_t)g*H_ + cell] = h;  // fp32 state
    __syncthreads();
  }
}

// ---------------------------------------------------------------------------
// Head: out[b][o] = h_last[b] . lin_w[o] + lin_b[o]
// ---------------------------------------------------------------------------
__global__ void head_kernel(const float* __restrict__ hfinal,
                            const float* __restrict__ lw,
                            const float* __restrict__ lb,
                            float* __restrict__ out)
{
  int idx = blockIdx.x*blockDim.x + threadIdx.x;
  if (idx >= B_*OUT_) return;
  int b = idx / OUT_, o = idx % OUT_;
  const float* h = hfinal + (size_t)b*H_;
  const float* wv = lw + (size_t)o*H_;
  float s = lb[o];
  #pragma unroll 8
  for (int k = 0; k < H_; ++k) s += h[k]*wv[k];
  out[idx] = s;
}

extern "C" void kernel_launch(void* const* d_in, const int* in_sizes, int n_in,
                              void* d_out, int out_size, void* d_ws, size_t ws_size,
                              hipStream_t stream) {
  const float* inputs = (const float*)d_in[0];
  const float* conv_w = (const float*)d_in[3];
  const float* conv_b = (const float*)d_in[4];
  const float* w_ih   = (const float*)d_in[5];
  const float* w_hh   = (const float*)d_in[6];
  const float* b_ih   = (const float*)d_in[7];
  const float* b_hh   = (const float*)d_in[8];
  const float* lin_w  = (const float*)d_in[9];
  const float* lin_b  = (const float*)d_in[10];

  float* actT   = (float*)d_ws;
  float* hfinal = (float*)((char*)d_ws + HFINAL_OFF);

  // no cross-WG sync buffers, no memsets: trivially graph-replay safe
  hipLaunchKernelGGL(conv_kernel, dim3(B_*16), dim3(512), 192*128*4, stream,
                     inputs, conv_w, conv_b, actT);
  hipLaunchKernelGGL(lstm_kernel, dim3(B_), dim3(1024), 0, stream,
                     actT, w_ih, w_hh, b_ih, b_hh, hfinal);
  hipLaunchKernelGGL(head_kernel, dim3(3), dim3(256), 0, stream,
                     hfinal, lin_w, lin_b, (float*)d_out);
}

// Round 16
// 2568.117 us; speedup vs baseline: 2.1720x; 2.1720x over previous
//
#include <hip/hip_runtime.h>
#include <math.h>

#define B_   64
#define S_   3072
#define DIN  128
#define E_   64
#define H_   256
#define OUT_ 10
#define T_   1024

// workspace layout (bytes)
#define ACT_BYTES   (B_*E_*T_*4)              // actT[b][e][t] fp32 = 16 MB
#define G_OFF       ACT_BYTES
#define G_BYTES     ((size_t)B_*1024*T_*2)    // G[b][r][t] fp16 = 128 MB
#define HFINAL_OFF  (G_OFF + G_BYTES)
#define HFINAL_BYTES (B_*H_*4)

typedef float f32x4 __attribute__((ext_vector_type(4)));
typedef _Float16 h16x2 __attribute__((ext_vector_type(2)));

#if defined(__has_builtin)
#  if __has_builtin(__builtin_amdgcn_fdot2)
#    define HAVE_FDOT2 1
#  endif
#endif

__device__ __forceinline__ float dot2acc(unsigned int w, unsigned int h, float acc) {
#ifdef HAVE_FDOT2
  union { unsigned int u; h16x2 v; } uw, uh;
  uw.u = w; uh.u = h;
  return __builtin_amdgcn_fdot2(uw.v, uh.v, acc, false);
#else
  union { unsigned int u; _Float16 f[2]; } uw, uh;
  uw.u = w; uh.u = h;
  acc = fmaf((float)uw.f[0], (float)uh.f[0], acc);
  acc = fmaf((float)uw.f[1], (float)uh.f[1], acc);
  return acc;
#endif
}

__device__ __forceinline__ unsigned int pack2(float a, float b) {
  union { _Float16 f[2]; unsigned int u; } r;
  r.f[0] = (_Float16)a; r.f[1] = (_Float16)b;
  return r.u;
}

__device__ __forceinline__ float fast_sigmoid(float x) {
  return __builtin_amdgcn_rcpf(1.0f + __expf(-x));
}
__device__ __forceinline__ float fast_tanh(float x) {
  return 2.0f * __builtin_amdgcn_rcpf(1.0f + __expf(-2.0f * x)) - 1.0f;
}

// ---------------------------------------------------------------------------
// Conv: normalize rows (L2 over D=128), conv1d k=3 stride=3, +bias, relu.
// (unchanged — validated rounds 1-15; ~30us, ~100 TF via uniform s_load wts)
// ---------------------------------------------------------------------------
__global__ __launch_bounds__(512, 1) void conv_kernel(
    const float* __restrict__ in,     // [B][S][DIN]
    const float* __restrict__ cw,     // [E][DIN][3]
    const float* __restrict__ cb,     // [E]
    float* __restrict__ actT)         // [B][E][T]
{
  extern __shared__ float xs[];                 // 192 rows x 128 f, swizzled
  float4* xs4 = (float4*)xs;
  const int bid = blockIdx.x;
  const int b  = bid >> 4;
  const int tb = bid & 15;
  const int tid = threadIdx.x;

  const float4* gin = (const float4*)(in + (size_t)b*S_*DIN + (size_t)tb*192*DIN);
  #pragma unroll
  for (int i = 0; i < 12; ++i) {
    int f4 = tid + i*512;
    int r = f4 >> 5, dq = f4 & 31;
    xs4[r*32 + (dq ^ (r & 7))] = gin[f4];
  }
  __syncthreads();

  const int wv = tid >> 6, ln = tid & 63;
  for (int rr = 0; rr < 24; ++rr) {
    int r = wv*24 + rr;
    int u = r*32 + ((ln >> 1) ^ (r & 7));
    float2* p = (float2*)((char*)xs + (size_t)u*16 + (size_t)(ln & 1)*8);
    float2 v = *p;
    float s = v.x*v.x + v.y*v.y;
    #pragma unroll
    for (int off = 32; off >= 1; off >>= 1) s += __shfl_xor(s, off);
    float inv = 1.0f / fmaxf(sqrtf(s), 1e-12f);
    v.x *= inv; v.y *= inv;
    *p = v;
  }
  __syncthreads();

  const int eo = __builtin_amdgcn_readfirstlane(wv);
  float acc[8];
  #pragma unroll
  for (int j = 0; j < 8; ++j) acc[j] = cb[eo*8 + j];

  const int r0 = 3*ln, r1 = 3*ln + 1, r2 = 3*ln + 2;
  #pragma unroll 4
  for (int dq = 0; dq < 32; ++dq) {
    float4 x0 = xs4[r0*32 + (dq ^ (r0 & 7))];
    float4 x1 = xs4[r1*32 + (dq ^ (r1 & 7))];
    float4 x2 = xs4[r2*32 + (dq ^ (r2 & 7))];
    #pragma unroll
    for (int j = 0; j < 8; ++j) {
      const float* wp = cw + (size_t)(eo*8 + j)*(DIN*3) + dq*12;  // uniform
      acc[j] += x0.x*wp[0] + x1.x*wp[1] + x2.x*wp[2]
              + x0.y*wp[3] + x1.y*wp[4] + x2.y*wp[5]
              + x0.z*wp[6] + x1.z*wp[7] + x2.z*wp[8]
              + x0.w*wp[9] + x1.w*wp[10] + x2.w*wp[11];
    }
  }

  const int tg = tb*64 + ln;
  #pragma unroll
  for (int j = 0; j < 8; ++j) {
    int e = eo*8 + j;
    actT[(size_t)b*E_*T_ + (size_t)e*T_ + tg] = fmaxf(acc[j], 0.0f);
  }
}

// ---------------------------------------------------------------------------
// xgate GEMM: G[b][r][t] = sum_e w_ih[r][e] * act[b][e][t]  (fp16, NO bias —
// keeps |G|~0.5 so fp16 quantization stays ~2e-4; bias added fp32 in LSTM).
// 512 WGs x 512 thr; WG = (b, 128 t's) in 2 tiles of 64. Wave w owns rows
// [128w,128w+128); lane = t. x tile staged LDS -> xv[64] regs; weights via
// wave-uniform s_load (conv-style ~80% fp32 peak). Stores 128B/wave coalesced.
// ---------------------------------------------------------------------------
__global__ __launch_bounds__(512, 1) void xgemm_kernel(
    const float* __restrict__ actT,   // [B][E][T]
    const float* __restrict__ w_ih,   // [1024][64]
    _Float16* __restrict__ G)         // [B][1024][T]
{
  __shared__ float xt[64][64];
  const int bid = blockIdx.x;
  const int b  = bid >> 3;
  const int tb = bid & 7;
  const int tid = threadIdx.x;
  const int w = __builtin_amdgcn_readfirstlane(tid >> 6);
  const int l = tid & 63;

  for (int tile = 0; tile < 2; ++tile) {
    const int t0 = tb*128 + tile*64;
    #pragma unroll
    for (int k = 0; k < 2; ++k) {
      int idx = tid + k*512;
      int e = idx >> 4, q4 = idx & 15;
      *(float4*)&xt[e][q4*4] =
          *(const float4*)(actT + ((size_t)b*E_ + e)*T_ + t0 + q4*4);
    }
    __syncthreads();
    float xv[64];
    #pragma unroll
    for (int e = 0; e < 64; ++e) xv[e] = xt[e][l];
    __syncthreads();

    for (int rr = 0; rr < 128; ++rr) {
      int r = w*128 + rr;
      const float* wp = w_ih + (size_t)r*E_;   // uniform -> s_load
      float acc = 0.0f;
      #pragma unroll
      for (int e = 0; e < 64; ++e) acc = fmaf(wp[e], xv[e], acc);
      G[((size_t)(b*1024 + r))*T_ + t0 + l] = (_Float16)acc;
    }
  }
}

// ---------------------------------------------------------------------------
// LSTM — single-WG-per-batch, ZERO cross-WG exchange (rounds 2-14's ~1.6us/
// step coherence RT is gone entirely). 64 WGs x 512 thr (8 waves = 2/SIMD ->
// 256 VGPR cap; r15's 1024-thr config capped at 128 and spilled).
// Thread = ONE cell's two gate rows: pr=tid&1 -> rows {2pr,2pr+1}*256+cell.
// w_hh fp16: 208 cols/row in VGPR (104 uint) + 48 cols/row in LDS
// ([512][49]-uint padded stride: 49 odd -> 2-way-free reads). x-projection
// G precomputed (xgemm) — read 2 fp16/thread/step, L2-line reuse x32 steps.
// Gate butterfly = ONE shfl_xor(1) pair exchange; one __syncthreads/step.
// State math fp32; only W/h/G operands fp16 (r15 measured absmax 4.9e-4).
// ---------------------------------------------------------------------------
__global__ __launch_bounds__(512, 1) void lstm_kernel(
    const _Float16* __restrict__ G,   // [B][1024][T]
    const float* __restrict__ w_hh,   // [1024][256]
    const float* __restrict__ b_ih,
    const float* __restrict__ b_hh,
    float* __restrict__ hfinal)       // [B][H]
{
  extern __shared__ unsigned int smem[];
  unsigned int* wlds = smem;                 // [512][49] (stride 49: 2-way-free)
  unsigned int* h2   = smem + 512*49;        // [2][128] f16x2 of h

  const int g   = blockIdx.x;          // batch
  const int tid = threadIdx.x;
  const int cell = tid >> 1;           // 0..255
  const int pr   = tid & 1;            // 0: gates (i,f); 1: gates (g,o)
  const int rA = (2*pr)*256 + cell;
  const int rB = (2*pr + 1)*256 + cell;

  // pack w_hh rows -> 104 VGPR uints each + 24 LDS uints each
  unsigned int wA[104], wB[104];
  {
    const float4* pa = (const float4*)(w_hh + (size_t)rA*H_);
    const float4* pb = (const float4*)(w_hh + (size_t)rB*H_);
    #pragma unroll
    for (int k = 0; k < 52; ++k) {
      float4 v = pa[k];
      wA[2*k] = pack2(v.x, v.y); wA[2*k+1] = pack2(v.z, v.w);
    }
    #pragma unroll
    for (int k = 0; k < 52; ++k) {
      float4 v = pb[k];
      wB[2*k] = pack2(v.x, v.y); wB[2*k+1] = pack2(v.z, v.w);
    }
    #pragma unroll
    for (int k = 52; k < 64; ++k) {
      float4 va = pa[k];
      wlds[tid*49 + 2*(k-52)]     = pack2(va.x, va.y);
      wlds[tid*49 + 2*(k-52) + 1] = pack2(va.z, va.w);
      float4 vb = pb[k];
      wlds[tid*49 + 24 + 2*(k-52)]     = pack2(vb.x, vb.y);
      wlds[tid*49 + 24 + 2*(k-52) + 1] = pack2(vb.z, vb.w);
    }
  }
  const float biasA = b_ih[rA] + b_hh[rA];
  const float biasB = b_ih[rB] + b_hh[rB];

  if (tid < 128) h2[tid] = 0u;         // h(0) = 0 (parity 0)
  __syncthreads();

  const _Float16* gA = G + (size_t)(g*1024 + rA)*T_;
  const _Float16* gB = G + (size_t)(g*1024 + rB)*T_;

  float c = 0.0f;
  for (int t = 0; t < T_; ++t) {
    const int p = t & 1;
    // independent loads — compiler issues early, L2-line reused 32 steps
    float aA = biasA + (float)gA[t];
    float aB = biasB + (float)gB[t];

    const unsigned int* hp = h2 + p*128;
    #pragma unroll
    for (int i = 0; i < 104; i += 4) {          // VGPR-weight part (cols 0..207)
      uint4 hv = *(const uint4*)(hp + i);
      aA = dot2acc(wA[i],   hv.x, aA);
      aA = dot2acc(wA[i+1], hv.y, aA);
      aA = dot2acc(wA[i+2], hv.z, aA);
      aA = dot2acc(wA[i+3], hv.w, aA);
      aB = dot2acc(wB[i],   hv.x, aB);
      aB = dot2acc(wB[i+1], hv.y, aB);
      aB = dot2acc(wB[i+2], hv.z, aB);
      aB = dot2acc(wB[i+3], hv.w, aB);
    }
    #pragma unroll
    for (int i = 0; i < 24; i += 4) {           // LDS-weight part (cols 208..255)
      uint4 hv = *(const uint4*)(hp + 104 + i);
      aA = dot2acc(wlds[tid*49 + i],     hv.x, aA);
      aA = dot2acc(wlds[tid*49 + i + 1], hv.y, aA);
      aA = dot2acc(wlds[tid*49 + i + 2], hv.z, aA);
      aA = dot2acc(wlds[tid*49 + i + 3], hv.w, aA);
      aB = dot2acc(wlds[tid*49 + 24 + i],     hv.x, aB);
      aB = dot2acc(wlds[tid*49 + 24 + i + 1], hv.y, aB);
      aB = dot2acc(wlds[tid*49 + 24 + i + 2], hv.z, aB);
      aB = dot2acc(wlds[tid*49 + 24 + i + 3], hv.w, aB);
    }

    // pair butterfly: partner lane holds the other two gates of this cell
    float xA = __shfl_xor(aA, 1);
    float xB = __shfl_xor(aB, 1);
    float gi = pr ? xA : aA;
    float gf = pr ? xB : aB;
    float gg = pr ? aA : xA;
    float go = pr ? aB : xB;

    float si = fast_sigmoid(gi);
    float sf = fast_sigmoid(gf);
    float so = fast_sigmoid(go);
    c = sf*c + si*fast_tanh(gg);
    float h = so*fast_tanh(c);

    if (pr == 0) {
      ((_Float16*)(h2 + (p ^ 1)*128))[cell] = (_Float16)h;
      if (t == T_ - 1) hfinal[(size_t)g*H_ + cell] = h;   // fp32 state out
    }
    __syncthreads();
  }
}

// ---------------------------------------------------------------------------
// Head: out[b][o] = h_last[b] . lin_w[o] + lin_b[o]
// ---------------------------------------------------------------------------
__global__ void head_kernel(const float* __restrict__ hfinal,
                            const float* __restrict__ lw,
                            const float* __restrict__ lb,
                            float* __restrict__ out)
{
  int idx = blockIdx.x*blockDim.x + threadIdx.x;
  if (idx >= B_*OUT_) return;
  int b = idx / OUT_, o = idx % OUT_;
  const float* h = hfinal + (size_t)b*H_;
  const float* wv = lw + (size_t)o*H_;
  float s = lb[o];
  #pragma unroll 8
  for (int k = 0; k < H_; ++k) s += h[k]*wv[k];
  out[idx] = s;
}

extern "C" void kernel_launch(void* const* d_in, const int* in_sizes, int n_in,
                              void* d_out, int out_size, void* d_ws, size_t ws_size,
                              hipStream_t stream) {
  const float* inputs = (const float*)d_in[0];
  const float* conv_w = (const float*)d_in[3];
  const float* conv_b = (const float*)d_in[4];
  const float* w_ih   = (const float*)d_in[5];
  const float* w_hh   = (const float*)d_in[6];
  const float* b_ih   = (const float*)d_in[7];
  const float* b_hh   = (const float*)d_in[8];
  const float* lin_w  = (const float*)d_in[9];
  const float* lin_b  = (const float*)d_in[10];

  float*     actT   = (float*)d_ws;
  _Float16*  G      = (_Float16*)((char*)d_ws + G_OFF);
  float*     hfinal = (float*)((char*)d_ws + HFINAL_OFF);

  // all workspace regions fully written before read each launch — replay-safe
  hipLaunchKernelGGL(conv_kernel, dim3(B_*16), dim3(512), 192*128*4, stream,
                     inputs, conv_w, conv_b, actT);
  hipLaunchKernelGGL(xgemm_kernel, dim3(B_*8), dim3(512), 0, stream,
                     actT, w_ih, G);
  hipLaunchKernelGGL(lstm_kernel, dim3(B_), dim3(512),
                     (512*49 + 256)*4, stream,
                     G, w_hh, b_ih, b_hh, hfinal);
  hipLaunchKernelGGL(head_kernel, dim3(3), dim3(256), 0, stream,
                     hfinal, lin_w, lin_b, (float*)d_out);
}